// Round 9
// baseline (359.203 us; speedup 1.0000x reference)
//
#include <hip/hip_runtime.h>

typedef unsigned short u16;
typedef __attribute__((ext_vector_type(8))) short bf16x8_t;
typedef __attribute__((ext_vector_type(4))) float f32x4_t;
typedef __attribute__((ext_vector_type(16))) float f32x16_t;

__device__ __forceinline__ u16 f2bf(float x){
  union { float f; unsigned u; } v; v.f = x;
  unsigned r = v.u + 0x7FFFu + ((v.u >> 16) & 1u);
  return (u16)(r >> 16);
}
__device__ __forceinline__ float bf2f(u16 h){
  union { unsigned u; float f; } v; v.u = ((unsigned)h) << 16;
  return v.f;
}
// truncation-pack two f32 -> (bf16(a) | bf16(b)<<16); bias cancels in renormalization
__device__ __forceinline__ unsigned pack_hi16(float a, float b){
  union { float f; unsigned u; } x, y; x.f = a; y.f = b;
  return (x.u >> 16) | (y.u & 0xFFFF0000u);
}

// async global->LDS DMA, 16B/lane; data lands at base + lane*16.
__device__ __forceinline__ void gl2lds16(const u16* g, u16* l){
  __builtin_amdgcn_global_load_lds((const __attribute__((address_space(1))) void*)g,
                                   (__attribute__((address_space(3))) void*)l, 16, 0, 0);
}

// ---- X = [gene|expr] concat, split into hi/lo bf16. 8192 rows x 1024 cols ----
__global__ __launch_bounds__(256) void split_concat_kernel(
    const float* __restrict__ gene, const float* __restrict__ expr,
    u16* __restrict__ Xh, u16* __restrict__ Xl)
{
  size_t e = ((size_t)blockIdx.x * 256 + threadIdx.x) * 4;
  int row = (int)(e >> 10);
  int col = (int)(e & 1023);
  const float* src = (col < 512) ? (gene + (size_t)row * 512 + col)
                                 : (expr + (size_t)row * 512 + (col - 512));
  float4 v = *(const float4*)src;
  float a[4] = {v.x, v.y, v.z, v.w};
  u16 hs[4], ls[4];
#pragma unroll
  for (int i = 0; i < 4; i++){
    hs[i] = f2bf(a[i]);
    ls[i] = f2bf(a[i] - bf2f(hs[i]));
  }
  *(uint2*)(Xh + e) = make_uint2(hs[0] | ((unsigned)hs[1] << 16), hs[2] | ((unsigned)hs[3] << 16));
  *(uint2*)(Xl + e) = make_uint2(ls[0] | ((unsigned)ls[1] << 16), ls[2] | ((unsigned)ls[3] << 16));
}

// ---- Wv, Wo transposes. W [512][512] f32 -> Wt [n][k] bf16 hi ----
__global__ __launch_bounds__(256) void transpose_vo_kernel(
    const float* __restrict__ Wv, const float* __restrict__ Wo,
    u16* __restrict__ Wvth, u16* __restrict__ Woth)
{
  __shared__ float t[64][65];
  int id = blockIdx.x;
  const float* W = (id < 64) ? Wv : Wo;
  u16* Th = (id < 64) ? Wvth : Woth;
  int tt = id & 63;
  int kx = tt >> 3, ny = tt & 7;
  int k0 = kx * 64, n0 = ny * 64;
  int tid = threadIdx.x;
  int r = tid >> 4;
  int c4 = (tid & 15) * 4;
#pragma unroll
  for (int p = 0; p < 4; p++){
    int k = p * 16 + r;
    float4 v = *(const float4*)(W + (size_t)(k0 + k) * 512 + n0 + c4);
    t[c4 + 0][k] = v.x; t[c4 + 1][k] = v.y; t[c4 + 2][k] = v.z; t[c4 + 3][k] = v.w;
  }
  __syncthreads();
#pragma unroll
  for (int p = 0; p < 4; p++){
    int n = p * 16 + r;
    u16 hs[4];
#pragma unroll
    for (int i = 0; i < 4; i++) hs[i] = f2bf(t[n][c4 + i]);
    size_t o = (size_t)(n0 + n) * 512 + k0 + c4;
    *(uint2*)(Th + o) = make_uint2(hs[0] | ((unsigned)hs[1] << 16), hs[2] | ((unsigned)hs[3] << 16));
  }
}

// ---- composite weights: Wfq = Wf@Wq, Wfk = Wf@Wk; stored transposed bf16-hi
// Bt[n][k], n in [0,512), k in [0,1024). fp32 accumulate (512-length dots).
// grid 256: bid>>7 = matrix (0=q,1=k); tile = 64k x 64n; j staged in 64-chunks.
__global__ __launch_bounds__(256) void wcomp_kernel(
    const float* __restrict__ Wf, const float* __restrict__ Wq,
    const float* __restrict__ Wk, u16* __restrict__ Bqt, u16* __restrict__ Bkt)
{
  __shared__ float tF[64][65];
  __shared__ float tW[64][65];
  int bid = blockIdx.x;
  int mat = bid >> 7, rest = bid & 127;
  int kt = rest >> 3, nt = rest & 7;
  const float* Wx = mat ? Wk : Wq;
  u16* Bt = mat ? Bkt : Bqt;
  int k0 = kt * 64, n0 = nt * 64;
  int tid = threadIdx.x;
  int r = tid >> 4, c4 = (tid & 15) * 4;
  int tk = (tid >> 4) * 4, tn = (tid & 15) * 4;

  float acc[4][4];
#pragma unroll
  for (int a = 0; a < 4; a++)
#pragma unroll
    for (int b = 0; b < 4; b++) acc[a][b] = 0.f;

  for (int j0 = 0; j0 < 512; j0 += 64){
    __syncthreads();
#pragma unroll
    for (int p = 0; p < 4; p++){
      int row = p * 16 + r;
      float4 a = *(const float4*)(Wf + (size_t)(k0 + row) * 512 + j0 + c4);
      *(float4*)&tF[row][c4] = a;
      float4 b = *(const float4*)(Wx + (size_t)(j0 + row) * 512 + n0 + c4);
      *(float4*)&tW[row][c4] = b;
    }
    __syncthreads();
#pragma unroll 8
    for (int jj = 0; jj < 64; jj++){
      float fa0 = tF[tk + 0][jj], fa1 = tF[tk + 1][jj];
      float fa2 = tF[tk + 2][jj], fa3 = tF[tk + 3][jj];
      float4 wb = *(const float4*)&tW[jj][tn];
      acc[0][0] += fa0 * wb.x; acc[0][1] += fa0 * wb.y; acc[0][2] += fa0 * wb.z; acc[0][3] += fa0 * wb.w;
      acc[1][0] += fa1 * wb.x; acc[1][1] += fa1 * wb.y; acc[1][2] += fa1 * wb.z; acc[1][3] += fa1 * wb.w;
      acc[2][0] += fa2 * wb.x; acc[2][1] += fa2 * wb.y; acc[2][2] += fa2 * wb.z; acc[2][3] += fa2 * wb.w;
      acc[3][0] += fa3 * wb.x; acc[3][1] += fa3 * wb.y; acc[3][2] += fa3 * wb.z; acc[3][3] += fa3 * wb.w;
    }
  }
#pragma unroll
  for (int b = 0; b < 4; b++){
    u16 h0 = f2bf(acc[0][b]), h1 = f2bf(acc[1][b]);
    u16 h2 = f2bf(acc[2][b]), h3 = f2bf(acc[3][b]);
    *(uint2*)(Bt + (size_t)(n0 + tn + b) * 1024 + k0 + tk) =
        make_uint2(h0 | ((unsigned)h1 << 16), h2 | ((unsigned)h3 << 16));
  }
}

// ---- composite biases: bq2 = bf@Wq + bq ; bk2 = bf@Wk + bk ----
__global__ __launch_bounds__(256) void bcomp_kernel(
    const float* __restrict__ Wq, const float* __restrict__ Wk,
    const float* __restrict__ bfv, const float* __restrict__ bq,
    const float* __restrict__ bk, float* __restrict__ bq2, float* __restrict__ bk2)
{
  int mat = blockIdx.x;
  const float* W = mat ? Wk : Wq;
  const float* bb = mat ? bk : bq;
  float* ob = mat ? bk2 : bq2;
  int tid = threadIdx.x;
  for (int n = tid; n < 512; n += 256){
    float a = bb[n];
    for (int j = 0; j < 512; j++)
      a += bfv[j] * W[(size_t)j * 512 + n];
    ob[n] = a;
  }
}

// ---- fused Q/K/V projection, ONE 1536-block dispatch (3 sides x 512 blocks).
// side 0: Qh = X @ Bqt + bq2, scaled by qsc (bf16 MODE1)
// side 1: Kh = X @ Bkt + bk2             (bf16 MODE1)
// side 2: Vt = X[:,512:] @ Wvth + bv -> V^T per head (MODE2), K=512
// A = X hi+lo split (SPLITS=2: aH*bH + aL*bH). BM=128 BN=64 BK=32, 4 waves.
// Double-buffered single-barrier K-loop (stage next -> compute cur -> barrier).
// LDS 40KB -> 4 blocks/CU possible; __launch_bounds__(256,3) caps VGPR at 168.
// 1536 blocks = 3-4 co-resident/CU (vs 2 before): the occupancy lever the
// R7/R8 nulls pointed at. XCD m-remap kept (requires gridDim.x==64).
__global__ __launch_bounds__(256, 3) void qkv_kernel(
    const u16* __restrict__ Xh, const u16* __restrict__ Xl,
    const u16* __restrict__ Bq, const u16* __restrict__ Bk, const u16* __restrict__ Bv,
    const float* __restrict__ bq2, const float* __restrict__ bk2, const float* __restrict__ bv,
    u16* __restrict__ Qh, u16* __restrict__ Kh, u16* __restrict__ Vt, float qsc)
{
  __shared__ __align__(16) u16 sAh[2][4096];
  __shared__ __align__(16) u16 sAl[2][4096];
  __shared__ __align__(16) u16 sBh[2][2048];
  int tid = threadIdx.x;
  int lane = tid & 63, w = tid >> 6, quad = lane >> 4, l15 = lane & 15;
  int wm = w & 1, wn = w >> 1;
  int lid = (int)(blockIdx.y * gridDim.x + blockIdx.x);
  int side = lid >> 9;
  int l = lid & 511;
  int m0 = (((l & 7) << 3) | ((l >> 3) & 7)) * 128;
  int n0 = (l >> 6) * 64;
  const u16* Bh = (side == 0) ? Bq : (side == 1) ? Bk : Bv;
  const float* bias = (side == 0) ? bq2 : (side == 1) ? bk2 : bv;
  int K = (side == 2) ? 512 : 1024;
  int aoff = (side == 2) ? 512 : 0;
  float sc = (side == 0) ? qsc : 1.f;

  f32x4_t acc[4][2];
#pragma unroll
  for (int i = 0; i < 4; i++)
#pragma unroll
    for (int j = 0; j < 2; j++)
#pragma unroll
      for (int r = 0; r < 4; r++) acc[i][j][r] = 0.f;

  int lrow = lane >> 2;
  int swzS = ((lane >> 2) & 3) ^ ((lane >> 4) & 3);
  int gkq  = ((lane & 3) ^ swzS) * 8;
  const u16* pAh0 = Xh + (size_t)(m0 + w * 32 + lrow) * 1024 + aoff + gkq;
  const u16* pAh1 = Xh + (size_t)(m0 + w * 32 + 16 + lrow) * 1024 + aoff + gkq;
  const u16* pAl0 = Xl + (size_t)(m0 + w * 32 + lrow) * 1024 + aoff + gkq;
  const u16* pAl1 = Xl + (size_t)(m0 + w * 32 + 16 + lrow) * 1024 + aoff + gkq;
  const u16* pBh0 = Bh + (size_t)(n0 + w * 16 + lrow) * K + gkq;

  int pq = (quad ^ ((l15 & 3) ^ ((l15 >> 2) & 3))) * 8;

#define STAGEQ(B, KK) do {                                                 \
    gl2lds16(pAh0 + (KK), &sAh[B][w * 1024]);                              \
    gl2lds16(pAh1 + (KK), &sAh[B][w * 1024 + 512]);                        \
    gl2lds16(pAl0 + (KK), &sAl[B][w * 1024]);                              \
    gl2lds16(pAl1 + (KK), &sAl[B][w * 1024 + 512]);                        \
    gl2lds16(pBh0 + (KK), &sBh[B][w * 512]);                               \
  } while (0)

  STAGEQ(0, 0);
  __syncthreads();

  int T = K >> 5;
  for (int t = 0; t < T; ++t){
    int ph = t & 1;
    bool nx = (t + 1) < T;
    if (nx) STAGEQ(ph ^ 1, (t + 1) * 32);

    bf16x8_t aH[4], aL[4], bH[2];
#pragma unroll
    for (int mi = 0; mi < 4; mi++){
      int ad = (wm * 64 + mi * 16 + l15) * 32 + pq;
      aH[mi] = *(const bf16x8_t*)&sAh[ph][ad];
      aL[mi] = *(const bf16x8_t*)&sAl[ph][ad];
    }
#pragma unroll
    for (int ni = 0; ni < 2; ni++){
      int bd = (wn * 32 + ni * 16 + l15) * 32 + pq;
      bH[ni] = *(const bf16x8_t*)&sBh[ph][bd];
    }
#pragma unroll
    for (int mi = 0; mi < 4; mi++)
#pragma unroll
      for (int ni = 0; ni < 2; ni++){
        acc[mi][ni] = __builtin_amdgcn_mfma_f32_16x16x32_bf16(aH[mi], bH[ni], acc[mi][ni], 0, 0, 0);
        acc[mi][ni] = __builtin_amdgcn_mfma_f32_16x16x32_bf16(aL[mi], bH[ni], acc[mi][ni], 0, 0, 0);
      }

    if (nx) __syncthreads();
  }
#undef STAGEQ

  u16* out = (side == 0) ? Qh : (side == 1) ? Kh : Vt;
#pragma unroll
  for (int mi = 0; mi < 4; mi++)
#pragma unroll
    for (int ni = 0; ni < 2; ni++){
      int gn = n0 + wn * 32 + ni * 16 + l15;
      float bs = bias[gn];
      int gm0 = m0 + wm * 64 + mi * 16 + quad * 4;
#pragma unroll
      for (int r = 0; r < 4; r++){
        float v = acc[mi][ni][r] + bs;
        int gm = gm0 + r;
        if (side < 2){
          out[(size_t)gm * 512 + gn] = f2bf(v * sc);
        } else {
          int bb = gm >> 11, s = gm & 2047;
          int hh = gn >> 6, d = gn & 63;
          out[((size_t)((bb * 8 + hh) * 64 + d) << 11) + s] = f2bf(v);
        }
      }
    }
}

// ---- O-projection GEMM (SPLITS=1, f32 out). Double-buffered single-barrier
// K-loop; XCD m-remap (requires gridDim.x==64, 512 blocks). ----
template<int SPLITS, int MODE, int DUAL>
__global__ __launch_bounds__(256, 2) void gemm_kernel(
    const u16* __restrict__ Ah, const u16* __restrict__ Al, int lda,
    const u16* __restrict__ Bh0, const u16* __restrict__ Bl0,
    const u16* __restrict__ Bh1, int K,
    const float* __restrict__ bias0, const float* __restrict__ bias1,
    void* __restrict__ out0, void* __restrict__ out1, void* __restrict__ outsec,
    float sc0, float sc1)
{
  __shared__ __align__(16) u16 sAh[2][128 * 32];
  __shared__ __align__(16) u16 sAl[SPLITS >= 2 ? 2 : 1][SPLITS >= 2 ? 128 * 32 : 8];
  __shared__ __align__(16) u16 sBh[2][64 * 32];
  __shared__ __align__(16) u16 sBl[SPLITS == 3 ? 2 : 1][SPLITS == 3 ? 64 * 32 : 8];
  int tid = threadIdx.x;
  int lane = tid & 63, w = tid >> 6, quad = lane >> 4, l15 = lane & 15;
  int wm = w & 1, wn = w >> 1;
  int lid = (int)(blockIdx.y * gridDim.x + blockIdx.x);
  int side = DUAL ? (lid >> 9) : 0;
  int l = lid & 511;
  int m0 = (((l & 7) << 3) | ((l >> 3) & 7)) * 128;
  int n0 = (l >> 6) * 64;
  const u16* Bh = (DUAL && side) ? Bh1 : Bh0;
  const float* bias = (DUAL && side) ? bias1 : bias0;
  void* o0 = (DUAL && side) ? outsec : out0;
  float sc = (DUAL && side) ? sc1 : sc0;

  f32x4_t acc[4][2];
#pragma unroll
  for (int i = 0; i < 4; i++)
#pragma unroll
    for (int j = 0; j < 2; j++)
#pragma unroll
      for (int r = 0; r < 4; r++) acc[i][j][r] = 0.f;

  int lrow = lane >> 2;
  int swzS = ((lane >> 2) & 3) ^ ((lane >> 4) & 3);
  int gkq  = ((lane & 3) ^ swzS) * 8;
  const u16* pAh0 = Ah + (size_t)(m0 + w * 32 + lrow) * lda + gkq;
  const u16* pAh1 = Ah + (size_t)(m0 + w * 32 + 16 + lrow) * lda + gkq;
  const u16* pAl0 = (SPLITS >= 2) ? Al + (size_t)(m0 + w * 32 + lrow) * lda + gkq : nullptr;
  const u16* pAl1 = (SPLITS >= 2) ? Al + (size_t)(m0 + w * 32 + 16 + lrow) * lda + gkq : nullptr;
  const u16* pBh0 = Bh + (size_t)(n0 + w * 16 + lrow) * K + gkq;
  const u16* pBl0 = (SPLITS == 3) ? Bl0 + (size_t)(n0 + w * 16 + lrow) * K + gkq : nullptr;

  int pq = (quad ^ ((l15 & 3) ^ ((l15 >> 2) & 3))) * 8;

#define STAGEG(B, KK) do {                                                 \
    gl2lds16(pAh0 + (KK), &sAh[B][w * 1024]);                              \
    gl2lds16(pAh1 + (KK), &sAh[B][w * 1024 + 512]);                        \
    if constexpr (SPLITS >= 2){                                            \
      gl2lds16(pAl0 + (KK), &sAl[B][w * 1024]);                            \
      gl2lds16(pAl1 + (KK), &sAl[B][w * 1024 + 512]);                      \
    }                                                                      \
    gl2lds16(pBh0 + (KK), &sBh[B][w * 512]);                               \
    if constexpr (SPLITS == 3)                                             \
      gl2lds16(pBl0 + (KK), &sBl[B][w * 512]);                             \
  } while (0)

  STAGEG(0, 0);
  __syncthreads();

  int T = K >> 5;
  for (int t = 0; t < T; ++t){
    int ph = t & 1;
    bool nx = (t + 1) < T;
    if (nx) STAGEG(ph ^ 1, (t + 1) * 32);

    bf16x8_t aH[4], aL[4], bH[2], bL[2];
#pragma unroll
    for (int mi = 0; mi < 4; mi++){
      int ad = (wm * 64 + mi * 16 + l15) * 32 + pq;
      aH[mi] = *(const bf16x8_t*)&sAh[ph][ad];
      if constexpr (SPLITS >= 2) aL[mi] = *(const bf16x8_t*)&sAl[ph][ad];
    }
#pragma unroll
    for (int ni = 0; ni < 2; ni++){
      int bd = (wn * 32 + ni * 16 + l15) * 32 + pq;
      bH[ni] = *(const bf16x8_t*)&sBh[ph][bd];
      if constexpr (SPLITS == 3) bL[ni] = *(const bf16x8_t*)&sBl[ph][bd];
    }
#pragma unroll
    for (int mi = 0; mi < 4; mi++)
#pragma unroll
      for (int ni = 0; ni < 2; ni++){
        acc[mi][ni] = __builtin_amdgcn_mfma_f32_16x16x32_bf16(aH[mi], bH[ni], acc[mi][ni], 0, 0, 0);
        if constexpr (SPLITS == 3)
          acc[mi][ni] = __builtin_amdgcn_mfma_f32_16x16x32_bf16(aH[mi], bL[ni], acc[mi][ni], 0, 0, 0);
        if constexpr (SPLITS >= 2)
          acc[mi][ni] = __builtin_amdgcn_mfma_f32_16x16x32_bf16(aL[mi], bH[ni], acc[mi][ni], 0, 0, 0);
      }

    if (nx) __syncthreads();
  }
#undef STAGEG

#pragma unroll
  for (int mi = 0; mi < 4; mi++)
#pragma unroll
    for (int ni = 0; ni < 2; ni++){
      int gn = n0 + wn * 32 + ni * 16 + l15;
      float bs = bias[gn];
      int gm0 = m0 + wm * 64 + mi * 16 + quad * 4;
#pragma unroll
      for (int r = 0; r < 4; r++){
        float v = acc[mi][ni][r] + bs;
        int gm = gm0 + r;
        if constexpr (MODE == 0){
          u16 hb = f2bf(v);
          ((u16*)o0)[(size_t)gm * 512 + gn] = hb;
          ((u16*)out1)[(size_t)gm * 512 + gn] = f2bf(v - bf2f(hb));
        } else if constexpr (MODE == 1){
          ((u16*)o0)[(size_t)gm * 512 + gn] = f2bf(v * sc);
        } else if constexpr (MODE == 2){
          int bb = gm >> 11, s = gm & 2047;
          int hh = gn >> 6, d = gn & 63;
          ((u16*)o0)[((size_t)((bb * 8 + hh) * 64 + d) << 11) + s] = f2bf(v);
        } else {
          ((float*)o0)[(size_t)gm * 512 + gn] = v;
        }
      }
    }
}

// ---- flash attention v5 (verified 84.5us, byte-identical): 32x32x16 MFMA core,
// register-P via kv-permutation. Block = 4 waves (wq q-half, wk kv-half),
// 2 heads/block. S^T = mfma(K,Q): C col = lane&31 = q, C row r holds
// kv = wk*32 + phi(r); phi chosen so post-softmax P sits EXACTLY in the PV
// B-operand layout lane-locally: zero LDS round-trip, zero cross-lane ops.
// K LDS swizzle key = kv bits {4,3,0}; V key = d&7 (swizzle applied on the
// per-lane GLOBAL source column; LDS dest linear per global_load_lds).
// M: 4 float4/lane/iter following phi, prefetched one tile ahead.
// wk-halves reduce O and l once at the end through LDS.
// grid (32,16): x = q-tile, y = b*4 + head-pair; 512 blocks = 2/CU.
__global__ __launch_bounds__(256, 2) void flash_kernel(
    const u16* __restrict__ Qh, const u16* __restrict__ Kh,
    const u16* __restrict__ Vt, const float* __restrict__ Mm,
    u16* __restrict__ Oh)
{
  __shared__ __align__(16) u16 sAll[2][16384];  // [buf][ K: 2h x 4096 | V: 2h x 4096 ]
  int tid = threadIdx.x, lane = tid & 63, w = tid >> 6;
  int ql = lane & 31, hi = lane >> 5;
  int wq = w >> 1, wk = w & 1;
  int by = blockIdx.y, b = by >> 2, h0 = (by & 3) * 2;
  int q0 = blockIdx.x * 64;
  int q  = q0 + wq * 32 + ql;

  // Q B-frags: lane holds Q[q][d = dt*16 + hi*8 + j]
  const u16* qp = Qh + ((size_t)(b * 2048 + q)) * 512 + h0 * 64 + hi * 8;
  bf16x8_t qf[2][4];
#pragma unroll
  for (int h = 0; h < 2; h++)
#pragma unroll
    for (int dt = 0; dt < 4; dt++)
      qf[h][dt] = *(const bf16x8_t*)(qp + h * 64 + dt * 16);

  // staging pointers: wave (wq=head, wk=row-half); 4 K-calls + 4 V-calls, 8 rows each
  int srow = lane >> 3, c8 = lane & 7;
  const u16* gK[4]; const u16* gV[4];
#pragma unroll
  for (int c = 0; c < 4; c++){
    int kv = wk * 32 + c * 8 + srow;                       // physical row in 64-tile
    int skey = ((c >> 1) << 2) | ((c & 1) << 1) | (srow & 1);   // kv bits {4,3,0}
    gK[c] = Kh + ((size_t)(b * 2048 + kv)) * 512 + (h0 + wq) * 64 + ((c8 ^ skey) << 3);
    gV[c] = Vt + ((size_t)((b * 8 + h0 + wq) * 64 + kv)) * 2048 + ((c8 ^ srow) << 3);
  }
  int dO = wq * 4096 + wk * 2048;   // u16 offset (within K or V section)

  // QK read: A row m=ql -> LDS row kvL = wk*32 + phi(ql)
  int phi = ((ql >> 3) & 1) * 16 + ((ql >> 2) & 1) * 8 + (ql >> 4) * 4 + (ql & 3);
  int kvL = wk * 32 + phi;
  int skr = ((ql >> 3) & 1) * 4 + ((ql >> 2) & 1) * 2 + (ql & 1);  // = key(kvL)
  int kaddr[4];
#pragma unroll
  for (int dt = 0; dt < 4; dt++)
    kaddr[dt] = kvL * 64 + (((dt * 2 + hi) ^ skr) << 3);
  // PV read: A row = d_local = ql; col chunk = wk*4 + kt*2 + hi, key = d&7
  int vaddr[2][2];
#pragma unroll
  for (int dn = 0; dn < 2; dn++)
#pragma unroll
    for (int kt = 0; kt < 2; kt++)
      vaddr[dn][kt] = (dn * 32 + ql) * 64 + (((wk * 4 + kt * 2 + hi) ^ (ql & 7)) << 3);

  // M: element reg of S -> kv = wk*32 + hi*8 + (g&1)*16 + (g>>1)*4 + e
  const float* mp = Mm + (size_t)b * (2048 * 2048) + (size_t)q * 2048 + wk * 32 + hi * 8;
  const int og[4] = {0, 16, 4, 20};

  float lp[2] = {0.f, 0.f};
  f32x16_t Oc[2][2];
#pragma unroll
  for (int h = 0; h < 2; h++)
#pragma unroll
    for (int dn = 0; dn < 2; dn++)
#pragma unroll
      for (int r = 0; r < 16; r++) Oc[h][dn][r] = 0.f;

#define STAGE(B, KK) do {                                              \
    _Pragma("unroll")                                                  \
    for (int c = 0; c < 4; c++){                                       \
      gl2lds16(gK[c] + (size_t)(KK) * 512, &sAll[B][dO + c * 512]);    \
      gl2lds16(gV[c] + (KK),               &sAll[B][8192 + dO + c * 512]); \
    }                                                                  \
  } while (0)

  // prologue
  STAGE(0, 0);
  f32x4_t Mc[4], Mn[4];
#pragma unroll
  for (int g = 0; g < 4; g++) Mc[g] = *(const f32x4_t*)(mp + og[g]);
  __syncthreads();

  for (int t = 0; t < 32; ++t){
    int ph = t & 1;
    bool nx = t < 31;
    if (nx) STAGE(ph ^ 1, (t + 1) * 64);
    if (nx){
#pragma unroll
      for (int g = 0; g < 4; g++) Mn[g] = *(const f32x4_t*)(mp + (t + 1) * 64 + og[g]);
    }
    const u16* kb = &sAll[ph][0];
    const u16* vb = &sAll[ph][8192];

#pragma unroll
    for (int h = 0; h < 2; ++h){
      const u16* kbh = kb + h * 4096;
      const u16* vbh = vb + h * 4096;

      f32x16_t S;
#pragma unroll
      for (int r = 0; r < 16; r++) S[r] = 0.f;
#pragma unroll
      for (int dt = 0; dt < 4; dt++){
        bf16x8_t kf = *(const bf16x8_t*)&kbh[kaddr[dt]];
        S = __builtin_amdgcn_mfma_f32_32x32x16_bf16(kf, qf[h][dt], S, 0, 0, 0);
      }

      // p = M * exp2(s*M); lp accumulates; P packed into PV B-frags lane-locally
      float p[16];
#pragma unroll
      for (int g = 0; g < 4; g++)
#pragma unroll
        for (int e = 0; e < 4; e++){
          float m = Mc[g][e];
          float v = m * __builtin_amdgcn_exp2f(S[g * 4 + e] * m);
          lp[h] += v;
          p[g * 4 + e] = v;
        }
#pragma unroll
      for (int kt = 0; kt < 2; kt++){
        union { unsigned u[4]; bf16x8_t v8; } pb;
        pb.u[0] = pack_hi16(p[kt * 4 + 0], p[kt * 4 + 1]);
        pb.u[1] = pack_hi16(p[kt * 4 + 2], p[kt * 4 + 3]);
        pb.u[2] = pack_hi16(p[kt * 4 + 8], p[kt * 4 + 9]);
        pb.u[3] = pack_hi16(p[kt * 4 + 10], p[kt * 4 + 11]);
#pragma unroll
        for (int dn = 0; dn < 2; dn++){
          bf16x8_t vf = *(const bf16x8_t*)&vbh[vaddr[dn][kt]];
          Oc[h][dn] = __builtin_amdgcn_mfma_f32_32x32x16_bf16(vf, pb.v8, Oc[h][dn], 0, 0, 0);
        }
      }
    }

    __syncthreads();   // drains next-tile DMAs (issued pre-compute) + releases bufs
    if (nx){
#pragma unroll
      for (int g = 0; g < 4; g++) Mc[g] = Mn[g];
    }
  }
#undef STAGE

  // hi-halves hold disjoint kv -> sum across lane^32
  lp[0] += __shfl_xor(lp[0], 32);
  lp[1] += __shfl_xor(lp[1], 32);

  // reduce O and l across the two wk-halves via LDS (buffers are dead now)
  float* red = (float*)&sAll[0][0];
  float* lpr = red + 8192;
  if (wk){
#pragma unroll
    for (int h = 0; h < 2; h++){
#pragma unroll
      for (int dn = 0; dn < 2; dn++)
#pragma unroll
        for (int rq = 0; rq < 4; rq++){
          f32x4_t o;
          o[0] = Oc[h][dn][rq * 4 + 0]; o[1] = Oc[h][dn][rq * 4 + 1];
          o[2] = Oc[h][dn][rq * 4 + 2]; o[3] = Oc[h][dn][rq * 4 + 3];
          *(f32x4_t*)&red[((((wq * 2 + h) * 2 + dn) * 4 + rq) * 64 + lane) * 4] = o;
        }
      lpr[(wq * 2 + h) * 64 + lane] = lp[h];
    }
  }
  __syncthreads();
  if (!wk){
#pragma unroll
    for (int h = 0; h < 2; h++){
      float li = lp[h] + lpr[(wq * 2 + h) * 64 + lane];
      float inv = 1.0f / li;
      size_t ob = ((size_t)(b * 2048 + q)) * 512 + (h0 + h) * 64;
#pragma unroll
      for (int dn = 0; dn < 2; dn++)
#pragma unroll
        for (int rq = 0; rq < 4; rq++){
          f32x4_t o = *(const f32x4_t*)&red[((((wq * 2 + h) * 2 + dn) * 4 + rq) * 64 + lane) * 4];
          float v0 = (Oc[h][dn][rq * 4 + 0] + o[0]) * inv;
          float v1 = (Oc[h][dn][rq * 4 + 1] + o[1]) * inv;
          float v2 = (Oc[h][dn][rq * 4 + 2] + o[2]) * inv;
          float v3 = (Oc[h][dn][rq * 4 + 3] + o[3]) * inv;
          int d0 = dn * 32 + rq * 8 + hi * 4;
          unsigned w0 = (unsigned)f2bf(v0) | ((unsigned)f2bf(v1) << 16);
          unsigned w1 = (unsigned)f2bf(v2) | ((unsigned)f2bf(v3) << 16);
          *(uint2*)(Oh + ob + d0) = make_uint2(w0, w1);
        }
    }
  }
}

extern "C" void kernel_launch(void* const* d_in, const int* in_sizes, int n_in,
                              void* d_out, int out_size, void* d_ws, size_t ws_size,
                              hipStream_t stream)
{
  const float* gene = (const float*)d_in[0];
  const float* expr = (const float*)d_in[1];
  const float* Mm   = (const float*)d_in[2];
  const float* Wf   = (const float*)d_in[3];
  const float* bfv  = (const float*)d_in[4];
  const float* Wq   = (const float*)d_in[5];
  const float* bq   = (const float*)d_in[6];
  const float* Wk   = (const float*)d_in[7];
  const float* bk   = (const float*)d_in[8];
  const float* Wv   = (const float*)d_in[9];
  const float* bv   = (const float*)d_in[10];
  const float* Wo   = (const float*)d_in[11];
  const float* bo   = (const float*)d_in[12];
  float* out = (float*)d_out;

  char* ws = (char*)d_ws;
  size_t off = 0;
  auto alloc = [&](size_t bytes) -> void* {
    void* p = (void*)(ws + off);
    off += (bytes + 255) & ~(size_t)255;
    return p;
  };
  u16* Xh   = (u16*)alloc(8192ull * 1024 * 2);
  u16* Xl   = (u16*)alloc(8192ull * 1024 * 2);
  u16* Wvth = (u16*)alloc(512ull * 512 * 2);
  u16* Woth = (u16*)alloc(512ull * 512 * 2);
  u16* Bqt  = (u16*)alloc(512ull * 1024 * 2);
  u16* Bkt  = (u16*)alloc(512ull * 1024 * 2);
  float* bq2 = (float*)alloc(512 * 4);
  float* bk2 = (float*)alloc(512 * 4);
  u16* Qh   = (u16*)alloc(8192ull * 512 * 2);
  u16* Kh   = (u16*)alloc(8192ull * 512 * 2);
  u16* Vt   = (u16*)alloc(8192ull * 512 * 2);
  // X is dead after the QKV projection; attention output aliases it.
  u16* Oh = Xh;

  const float QSC = 0.1803368801f;   // 0.125 * log2(e) — folded into Q, exp via exp2

  split_concat_kernel<<<8192, 256, 0, stream>>>(gene, expr, Xh, Xl);
  transpose_vo_kernel<<<128, 256, 0, stream>>>(Wv, Wo, Wvth, Woth);
  // composite weights/biases: Q = X@(Wf@Wq) + (bf@Wq + bq), same for K
  wcomp_kernel<<<256, 256, 0, stream>>>(Wf, Wq, Wk, Bqt, Bkt);
  bcomp_kernel<<<2, 256, 0, stream>>>(Wq, Wk, bfv, bq, bk, bq2, bk2);
  // Q, K, V in ONE 1536-block dispatch (3-4 blocks/CU occupancy)
  qkv_kernel<<<dim3(64, 24), 256, 0, stream>>>(
      Xh, Xl, Bqt, Bkt, Wvth, bq2, bk2, bv, Qh, Kh, Vt, QSC);
  // attention: 32x32 core, 2 heads/block, kv-split waves
  flash_kernel<<<dim3(32, 16), 256, 0, stream>>>(Qh, Kh, Vt, Mm, Oh);
  // out = O @ Wo + bo -> f32 (pure bf16)
  gemm_kernel<1, 3, 0><<<dim3(64, 8), 256, 0, stream>>>(
      Oh, nullptr, 512, Woth, nullptr, nullptr, 512, bo, nullptr, out, nullptr, nullptr, 1.f, 1.f);

  (void)in_sizes; (void)n_in; (void)out_size; (void)ws_size;
}